// Round 12
// baseline (258.028 us; speedup 1.0000x reference)
//
#include <hip/hip_runtime.h>
#include <hip/hip_bf16.h>

#define BB 16
#define DDIM 256
#define TLEN 4096
#define KCODES 1024
#define NQ (BB*TLEN)   // 65536
#define QB 64          // queries per k_mdist block
#define MAXC 32

#define FLT_MAX_C 3.402823466e+38f

using short8 = __attribute__((ext_vector_type(8))) short;
using f32x4  = __attribute__((ext_vector_type(4))) float;

// RNE fp32 -> bf16 (bit pattern)
__device__ __forceinline__ unsigned short f2bf(float x) {
  unsigned u = __float_as_uint(x);
  unsigned r = (u + 0x7fffu + ((u >> 16) & 1u)) >> 16;
  return (unsigned short)r;
}

// ---------------------------------------------------------------------------
// numpy pairwise 8-accumulator block over 128 elements (half of n=256).
// np_sumsq_256(x) == fadd(block(x), block(x+128)) exactly.
// ---------------------------------------------------------------------------
__device__ __forceinline__ float np_sumsq_128(const float* q, int stride) {
  float r[8];
#pragma unroll
  for (int j = 0; j < 8; ++j) {
    float v = q[(size_t)j * (size_t)stride];
    r[j] = __fmul_rn(v, v);
  }
  for (int i = 8; i < 128; i += 8) {
#pragma unroll
    for (int j = 0; j < 8; ++j) {
      float v = q[(size_t)(i + j) * (size_t)stride];
      r[j] = __fadd_rn(r[j], __fmul_rn(v, v));
    }
  }
  return __fadd_rn(__fadd_rn(__fadd_rn(r[0], r[1]), __fadd_rn(r[2], r[3])),
                   __fadd_rn(__fadd_rn(r[4], r[5]), __fadd_rn(r[6], r[7])));
}
__device__ __forceinline__ float np_sumsq_256s(const float* p, int stride) {
  return __fadd_rn(np_sumsq_128(p, stride),
                   np_sumsq_128(p + (size_t)128 * stride, stride));
}

// ---------------------------------------------------------------------------
// k_prep: e2 exact, bf16-hi of emb [k][d], maxe = max|e| (bound input)
// ---------------------------------------------------------------------------
__global__ void k_prep(const float* __restrict__ emb, float* __restrict__ e2,
                       short* __restrict__ ebh, unsigned* __restrict__ maxe) {
  const int k = blockIdx.x;
  const int d = threadIdx.x;
  __shared__ float row[DDIM];
  float v = emb[(size_t)k * DDIM + d];
  row[d] = v;
  ebh[(size_t)k * DDIM + d] = (short)f2bf(v);
  float a = fabsf(v);
#pragma unroll
  for (int m = 1; m < 64; m <<= 1) a = fmaxf(a, __shfl_xor(a, m, 64));
  if ((threadIdx.x & 63) == 0) atomicMax(maxe, __float_as_uint(a));
  __syncthreads();
  if (d == 0) e2[k] = np_sumsq_256s(row, 1);
}

// ---------------------------------------------------------------------------
// k_mdist v8: 512 threads = 8 waves, block = 64 queries x 1024 codes.
// Wave w: all 64 q x codes [h*512 + w*64, +64) over two halves h=0,1.
// acc[4][4] f32x4 = 64 VGPR; ah[4]=16; bbuf[4]=16 (one-ks-ahead rotation)
// -> live ~111 <= 128 cap (empirical hipcc law: cap = 65536/threads).
// Filter: one MFMA pass (zh*eh). Per half: wave-min -> block qmin_h ->
// candidates with window 0.016*maxe*sabs_q + 2e-4 (>= adversarial bf16
// bound; per-half window is a superset of the global-min window).
// Exact fp32 recheck (reference chain, z from LDS) -> bit-exact argmin.
// LDS 110080B dynamic: zf 64K (live always) | abh 32K (bd/bk alias after
// MFMA) | persist tail 11.5K. 1 block/CU (LDS-bound), so VGPR is free.
// Fused: oidx + output gather + hist + loss partials.
// ---------------------------------------------------------------------------
__global__ __launch_bounds__(512, 1)
void k_mdist(const float* __restrict__ z, const float* __restrict__ emb,
             const short* __restrict__ ebh, const float* __restrict__ e2,
             const unsigned* __restrict__ maxeU, float* __restrict__ out,
             float* __restrict__ oidx, int* __restrict__ hist,
             double* __restrict__ lossp) {
  extern __shared__ __align__(16) char sbuf[];        // 110080 bytes
  float*  zf   = (float*)sbuf;                        // [256][64], live always
  short8* abh  = (short8*)(sbuf + 65536);             // [8ks][4mt][64lane]
  // alias into abh region (valid after both MFMA halves):
  float* bd    = (float*)(sbuf + 65536);              // [64][8]  2KB
  int*   bk    = (int*)(sbuf + 65536 + 2048);         // [64][8]  2KB
  // persistent tail (never aliased):
  float* sm    = (float*)(sbuf + 98304);              // [8][64]  2KB
  float* qmin  = (float*)(sbuf + 98304 + 2048);       // [64]
  int*   cand  = (int*)(sbuf + 98304 + 2304);         // [64][MAXC] 8KB
  int*   cnt   = (int*)(sbuf + 98304 + 10496);        // [64]
  int*   ovf   = (int*)(sbuf + 98304 + 10752);        // [64]
  float* z2s   = (float*)(sbuf + 98304 + 11008);      // [64]
  float* sabs  = (float*)(sbuf + 98304 + 11264);      // [64]
  int*   sidxs = (int*)(sbuf + 98304 + 11520);        // [64]

  const int tid = threadIdx.x;
  const int lane = tid & 63;
  const int w = tid >> 6;    // 0..7
  const int g = lane >> 4;   // 0..3
  const int c = lane & 15;
  const int n0 = blockIdx.x * QB;
  const int b = n0 >> 12;
  const int t0 = n0 & (TLEN - 1);
  const float* zp = z + (size_t)b * DDIM * TLEN + t0;

  // ---- 1. stage zf[d][q] (exact fp32), coalesced float4 ----
#pragma unroll
  for (int i = 0; i < 8; ++i) {
    int s4 = i * 512 + tid;            // 4096 float4 slots
    int dl = s4 >> 4, q4 = (s4 & 15) * 4;
    *(float4*)&zf[dl * QB + q4] = *(const float4*)(zp + (size_t)dl * TLEN + q4);
  }
  __syncthreads();

  // ---- 2. A-build + z2/sabs + cnt/ovf init ----
#pragma unroll
  for (int i = 0; i < 4; ++i) {
    int s = i * 512 + tid;             // 2048 slots: ks(8) x mt(4) x lane(64)
    int ks = s >> 8, mt = (s >> 6) & 3, ln = s & 63;
    int q = mt * 16 + (ln & 15);
    int d0 = ks * 32 + (ln >> 4) * 8;
    short8 hh;
#pragma unroll
    for (int j = 0; j < 8; ++j) hh[j] = (short)f2bf(zf[(d0 + j) * QB + q]);
    abh[s] = hh;
  }
  if (tid < QB) {
    z2s[tid] = np_sumsq_256s(&zf[tid], QB);
    float sa = 0.f;
    for (int d = 0; d < DDIM; ++d) sa += fabsf(zf[d * QB + tid]);
    sabs[tid] = sa;
    cnt[tid] = 0;
    ovf[tid] = 0;
  }
  __syncthreads();

  const float maxe = __uint_as_float(*maxeU);

  // ---- 3. two halves: MFMA (64q x 512c) + per-half filter ----
#pragma unroll 1
  for (int h = 0; h < 2; ++h) {
    const int kb = h * 512 + w * 64;

    f32x4 acc[4][4];
#pragma unroll
    for (int mt = 0; mt < 4; ++mt)
#pragma unroll
      for (int nt = 0; nt < 4; ++nt) {
        f32x4 zz = {0.f, 0.f, 0.f, 0.f};
        acc[mt][nt] = zz;
      }

    const short* ebp = ebh + (size_t)(kb + c) * DDIM + g * 8;
    short8 bbuf[4];
#pragma unroll
    for (int nt = 0; nt < 4; ++nt)
      bbuf[nt] = *(const short8*)(ebp + nt * (16 * DDIM));

    for (int ks = 0; ks < 8; ++ks) {
      short8 ah[4];
#pragma unroll
      for (int mt = 0; mt < 4; ++mt) ah[mt] = abh[ks * 256 + mt * 64 + lane];
      const int ksn = (ks + 1) & 7;
#pragma unroll
      for (int nt = 0; nt < 4; ++nt) {
        short8 bv = bbuf[nt];
        bbuf[nt] = *(const short8*)(ebp + nt * (16 * DDIM) + ksn * 32);
#pragma unroll
        for (int mt = 0; mt < 4; ++mt)
          acc[mt][nt] = __builtin_amdgcn_mfma_f32_16x16x32_bf16(
              ah[mt], bv, acc[mt][nt], 0, 0, 0);
      }
    }

    // per-half epilogue: wave min -> block qmin_h -> candidates
    float e2c[4];
#pragma unroll
    for (int nt = 0; nt < 4; ++nt) e2c[nt] = e2[kb + nt * 16 + c];

#pragma unroll
    for (int mt = 0; mt < 4; ++mt) {
      float m4[4];
#pragma unroll
      for (int r = 0; r < 4; ++r) {
        float m = FLT_MAX_C;
#pragma unroll
        for (int nt = 0; nt < 4; ++nt)
          m = fminf(m, e2c[nt] - 2.0f * acc[mt][nt][r]);
#pragma unroll
        for (int s = 1; s < 16; s <<= 1) m = fminf(m, __shfl_xor(m, s, 64));
        m4[r] = m;
      }
      if (c == 0) {
#pragma unroll
        for (int r = 0; r < 4; ++r) sm[w * 64 + mt * 16 + g * 4 + r] = m4[r];
      }
    }
    __syncthreads();
    if (tid < QB) {
      float m = sm[tid];
#pragma unroll
      for (int wv = 1; wv < 8; ++wv) m = fminf(m, sm[wv * 64 + tid]);
      qmin[tid] = m;
    }
    __syncthreads();

#pragma unroll
    for (int mt = 0; mt < 4; ++mt)
#pragma unroll
      for (int r = 0; r < 4; ++r) {
        const int ql = mt * 16 + g * 4 + r;
        const float lim = qmin[ql] + (maxe * sabs[ql]) * 0.016f + 2e-4f;
#pragma unroll
        for (int nt = 0; nt < 4; ++nt) {
          float s = e2c[nt] - 2.0f * acc[mt][nt][r];
          if (s <= lim) {
            int p = atomicAdd(&cnt[ql], 1);
            if (p < MAXC) cand[ql * MAXC + p] = kb + nt * 16 + c;
            else ovf[ql] = 1;
          }
        }
      }
    __syncthreads();  // cand done; sm reusable next half; abh reads resume
  }

  // ---- 4. exact recheck (reference fp32 chain; z from LDS), 8 slots/q ----
  {
    const int q = tid & 63;
    const int slot = tid >> 6;
    const float z2q = z2s[q];
    float bestd = FLT_MAX_C;
    int besti = (1 << 30);
    const bool all = (ovf[q] != 0) || (cnt[q] > MAXC);
    const int count = all ? KCODES : cnt[q];
    for (int ci = slot; ci < count; ci += 8) {
      const int k = all ? ci : cand[q * MAXC + ci];
      const float4* ek = (const float4*)(emb + (size_t)k * DDIM);
      float a0 = 0.f;
      for (int dd = 0; dd < 64; ++dd) {
        float4 e4 = ek[dd];
        a0 = __fmaf_rn(zf[(dd * 4 + 0) * QB + q], e4.x, a0);
        a0 = __fmaf_rn(zf[(dd * 4 + 1) * QB + q], e4.y, a0);
        a0 = __fmaf_rn(zf[(dd * 4 + 2) * QB + q], e4.z, a0);
        a0 = __fmaf_rn(zf[(dd * 4 + 3) * QB + q], e4.w, a0);
      }
      float dist = __fsub_rn(__fadd_rn(z2q, e2[k]), __fmul_rn(2.0f, a0));
      if (dist < bestd || (dist == bestd && k < besti)) { bestd = dist; besti = k; }
    }
    bd[q * 8 + slot] = bestd;
    bk[q * 8 + slot] = besti;
  }
  __syncthreads();

  // ---- 5. final per-query reduce; idx/loss/hist outputs ----
  if (tid < QB) {
    float B = bd[tid * 8 + 0];
    int K = bk[tid * 8 + 0];
#pragma unroll
    for (int s = 1; s < 8; ++s) {
      float d2 = bd[tid * 8 + s];
      int k2 = bk[tid * 8 + s];
      if (d2 < B || (d2 == B && k2 < K)) { B = d2; K = k2; }
    }
    K &= (KCODES - 1);
    sidxs[tid] = K;
    oidx[n0 + tid] = (float)K;
    atomicAdd(&hist[K], 1);
    double ls = (double)B;
#pragma unroll
    for (int m = 1; m < 64; m <<= 1) ls += __shfl_xor(ls, m, 64);
    if (tid == 0) lossp[blockIdx.x] = ls;
  }
  __syncthreads();

  // ---- 6. fused gather: out[b,d,t0+q] = emb[sidxs[q]][d] ----
  float* obase = out + (size_t)b * DDIM * TLEN + t0;
#pragma unroll
  for (int i = 0; i < 32; ++i) {
    int e = i * 512 + tid;   // 16384 elements
    int q = e & 63, d = e >> 6;
    obase[(size_t)d * TLEN + q] = emb[(size_t)sidxs[q] * DDIM + d];
  }
}

// ---------------------------------------------------------------------------
// k_final: loss and perplexity (deterministic fixed-tree reductions)
// ---------------------------------------------------------------------------
__global__ void k_final(const int* __restrict__ hist,
                        const double* __restrict__ lossp,
                        float* __restrict__ out2) {
  const int tid = threadIdx.x;  // 256
  double ls = 0.0;
  for (int i = 0; i < 4; ++i) ls += lossp[tid * 4 + i];  // 1024 partials
  float es = 0.f;
  for (int i = tid; i < KCODES; i += 256) {
    float p = (float)hist[i] / 65536.0f;
    es += p * logf(p + 1e-10f);
  }
#pragma unroll
  for (int m = 1; m < 64; m <<= 1) {
    ls += __shfl_xor(ls, m, 64);
    es += __shfl_xor(es, m, 64);
  }
  __shared__ double lw[4];
  __shared__ float ew[4];
  if ((tid & 63) == 0) { lw[tid >> 6] = ls; ew[tid >> 6] = es; }
  __syncthreads();
  if (tid == 0) {
    double lt = lw[0] + lw[1] + lw[2] + lw[3];
    float et = ew[0] + ew[1] + ew[2] + ew[3];
    float loss = 0.25f * (float)(lt / (double)((long long)NQ * DDIM));
    float perp = expf(-et);
    out2[0] = loss;
    out2[1] = perp;
  }
}

// ---------------------------------------------------------------------------
// workspace layout (bytes):
//   e2    : 0     .. 4096     (K floats)
//   hist  : 4096  .. 8192     (K ints)     <- memset each launch (with maxe)
//   maxe  : 8192  .. 8196     (1 uint)
//   lossp : 8200  .. 16392    (1024 doubles, fully written)
//   ebh   : 16400 .. 540688   (K*D bf16 hi)
// total ~0.54 MB
// ---------------------------------------------------------------------------
extern "C" void kernel_launch(void* const* d_in, const int* in_sizes, int n_in,
                              void* d_out, int out_size, void* d_ws, size_t ws_size,
                              hipStream_t stream) {
  const float* z = (const float*)d_in[0];
  const float* emb = (const float*)d_in[1];
  float* out = (float*)d_out;

  char* ws = (char*)d_ws;
  float* e2 = (float*)(ws);
  int* hist = (int*)(ws + 4096);
  unsigned* maxe = (unsigned*)(ws + 8192);
  double* lossp = (double*)(ws + 8200);
  short* ebh = (short*)(ws + 16400);

  float* oidx = out + ((size_t)out_size - 2 - NQ);
  float* out2 = out + ((size_t)out_size - 2);

  // dynamic LDS for k_mdist: 110080 bytes
  (void)hipFuncSetAttribute((const void*)k_mdist,
                            hipFuncAttributeMaxDynamicSharedMemorySize,
                            110080);

  hipMemsetAsync(hist, 0, 4100, stream);  // hist + maxe

  k_prep<<<KCODES, 256, 0, stream>>>(emb, e2, ebh, maxe);
  k_mdist<<<NQ / QB, 512, 110080, stream>>>(z, emb, ebh, e2, maxe, out, oidx,
                                            hist, lossp);
  k_final<<<1, 256, 0, stream>>>(hist, lossp, out2);
}